// Round 7
// baseline (235.697 us; speedup 1.0000x reference)
//
#include <hip/hip_runtime.h>

// Problem constants: B=16, T=64, N=128, D=512, H=512, O=256, A=18
#define DD 512
#define HH 512
#define OO 256
#define AA 18
#define ROWS 1024
#define NBLK 256
#define NTHR 256

// Flat LDS, phase-overlaid via constexpr-offset casts (no union, no dynamic
// indexing). Max user: P4 = 4608 (sW) + 4*260 (sT) = 5648 floats = 22.6 KB.
#define SMEM_FLOATS 5760

// Device-scope grid barrier (proven correct in round 5; all 256 blocks
// co-resident: 23KB LDS, 4 waves -> 1 block/CU, grid == CU count).
__device__ __forceinline__ void gridbar(unsigned* cnt, unsigned* gen) {
  __syncthreads();
  __threadfence();
  if (threadIdx.x == 0) {
    unsigned g = __hip_atomic_load(gen, __ATOMIC_RELAXED, __HIP_MEMORY_SCOPE_AGENT);
    unsigned a = __hip_atomic_fetch_add(cnt, 1u, __ATOMIC_ACQ_REL, __HIP_MEMORY_SCOPE_AGENT);
    if (a == NBLK - 1) {
      __hip_atomic_store(cnt, 0u, __ATOMIC_RELAXED, __HIP_MEMORY_SCOPE_AGENT);
      __hip_atomic_fetch_add(gen, 1u, __ATOMIC_RELEASE, __HIP_MEMORY_SCOPE_AGENT);
    } else {
      while (__hip_atomic_load(gen, __ATOMIC_ACQUIRE, __HIP_MEMORY_SCOPE_AGENT) == g)
        __builtin_amdgcn_s_sleep(2);
    }
  }
  __syncthreads();
  __threadfence();
}

__global__ __launch_bounds__(NTHR) void fused(
    const float* __restrict__ obs, const float* __restrict__ W1,
    const float* __restrict__ b1, const float* __restrict__ W2,
    const float* __restrict__ b2, const float* __restrict__ Wl,
    const float* __restrict__ bl, float* __restrict__ out,
    float* __restrict__ Gp, float* __restrict__ U, float* __restrict__ Tp,
    unsigned* __restrict__ cnt, unsigned* __restrict__ gen) {
  __shared__ float smem[SMEM_FLOATS];
  const int tid = threadIdx.x;
  const int blk = blockIdx.x;

  // ====== Phase 1: Gp[z] = obs @ W1 K-slice partials (KS=2) ======
  // Tile 64x64, BK=32, 8 tiles/block. Grid decode: (8 col, 16 row, 2 K).
  {
    float (*As)[64] = (float (*)[64])smem;          // [32][64] transposed
    float (*Bs)[64] = (float (*)[64])(smem + 2048); // [32][64]
    const int tx = tid & 15, ty = tid >> 4;
    const int col0 = (blk & 7) * 64;
    const int row0 = ((blk >> 3) & 15) * 64;
    const int k0 = (blk >> 7) * 256;
    float4 pa[2], pb[2];
    float acc[4][4] = {};

#define LOADG(kb)                                                              \
  {                                                                            \
    _Pragma("unroll") for (int q = 0; q < 2; ++q) {                            \
      int f = tid + q * 256;                                                   \
      int ar = f >> 3, ac = f & 7;                                             \
      pa[q] = *reinterpret_cast<const float4*>(                                \
          &obs[(size_t)(row0 + ar) * DD + (kb) + ac * 4]);                     \
    }                                                                          \
    _Pragma("unroll") for (int q = 0; q < 2; ++q) {                            \
      int f = tid + q * 256;                                                   \
      int br = f >> 4, bc = f & 15;                                            \
      pb[q] = *reinterpret_cast<const float4*>(                                \
          &W1[(size_t)((kb) + br) * HH + col0 + bc * 4]);                      \
    }                                                                          \
  }
#define STOLDS()                                                               \
  {                                                                            \
    _Pragma("unroll") for (int q = 0; q < 2; ++q) {                            \
      int f = tid + q * 256;                                                   \
      int ar = f >> 3, ac = f & 7;                                             \
      As[ac * 4 + 0][ar] = pa[q].x;                                            \
      As[ac * 4 + 1][ar] = pa[q].y;                                            \
      As[ac * 4 + 2][ar] = pa[q].z;                                            \
      As[ac * 4 + 3][ar] = pa[q].w;                                            \
    }                                                                          \
    _Pragma("unroll") for (int q = 0; q < 2; ++q) {                            \
      int f = tid + q * 256;                                                   \
      int br = f >> 4, bc = f & 15;                                            \
      *reinterpret_cast<float4*>(&Bs[br][bc * 4]) = pb[q];                     \
    }                                                                          \
  }
#define COMPUTE()                                                              \
  {                                                                            \
    _Pragma("unroll") for (int kk = 0; kk < 32; ++kk) {                        \
      float a[4], b[4];                                                        \
      _Pragma("unroll") for (int i = 0; i < 4; ++i) a[i] = As[kk][ty * 4 + i]; \
      _Pragma("unroll") for (int j = 0; j < 4; ++j) b[j] = Bs[kk][tx * 4 + j]; \
      _Pragma("unroll") for (int i = 0; i < 4; ++i)                            \
          _Pragma("unroll") for (int j = 0; j < 4; ++j)                        \
              acc[i][j] = fmaf(a[i], b[j], acc[i][j]);                         \
    }                                                                          \
  }

    LOADG(k0);
    STOLDS();
    __syncthreads();
    for (int kb = k0 + 32; kb < k0 + 256; kb += 32) {
      LOADG(kb);
      COMPUTE();
      __syncthreads();
      STOLDS();
      __syncthreads();
    }
    COMPUTE();
#undef LOADG
#undef STOLDS
#undef COMPUTE

    float* Pz = Gp + (size_t)(blk >> 7) * ROWS * HH;
#pragma unroll
    for (int i = 0; i < 4; ++i) {
      int r = row0 + ty * 4 + i;
#pragma unroll
      for (int j = 0; j < 4; ++j)
        Pz[(size_t)r * HH + col0 + tx * 4 + j] = acc[i][j];
    }
  }

  gridbar(cnt, gen);

  // ====== Phase 2: U = pathGCN1(reduce Gp) ======
  // 4 rows/block, 512 float4 items, 2 per thread.
  {
    constexpr size_t SZ = (size_t)ROWS * HH;
    const float is6 = 0.4082482904638630f;  // 1/sqrt(6)
    for (int it = tid; it < 512; it += NTHR) {
      const int r = blk * 4 + (it >> 7);
      const int k4 = (it & 127) * 4;
      const int t = r & 63;
      float c0, c1, c2, d1, d2, al, be;
      if (t <= 1) {
        c0 = 0.f; c1 = 0.f; c2 = 1.f; d1 = 0.f; d2 = 0.f; al = 1.f; be = 0.f;
      } else if (t == 2) {
        c0 = 0.f; c1 = 0.5f; c2 = 0.5f; d1 = 0.5f; d2 = 0.5f; al = 0.5f; be = 0.5f;
      } else {
        c0 = (t == 3) ? is6 : (1.f / 3.f);
        c1 = 1.f / 3.f; c2 = is6;
        d1 = is6; d2 = 0.5f;
        al = is6; be = 0.5f;
      }
      const int rm1 = (t >= 1) ? r - 1 : r;
      const int rm2 = (t >= 2) ? r - 2 : r;
      const size_t oc = (size_t)r * HH + k4;
      const size_t ob = (size_t)rm1 * HH + k4;
      const size_t oa = (size_t)rm2 * HH + k4;
      float4 gc = *reinterpret_cast<const float4*>(&Gp[oc]);
      float4 gb = *reinterpret_cast<const float4*>(&Gp[ob]);
      float4 ga = *reinterpret_cast<const float4*>(&Gp[oa]);
      const float4 gc2 = *reinterpret_cast<const float4*>(&Gp[SZ + oc]);
      const float4 gb2 = *reinterpret_cast<const float4*>(&Gp[SZ + ob]);
      const float4 ga2 = *reinterpret_cast<const float4*>(&Gp[SZ + oa]);
      gc.x += gc2.x; gc.y += gc2.y; gc.z += gc2.z; gc.w += gc2.w;
      gb.x += gb2.x; gb.y += gb2.y; gb.z += gb2.z; gb.w += gb2.w;
      ga.x += ga2.x; ga.y += ga2.y; ga.z += ga2.z; ga.w += ga2.w;
      const float4 bb = *reinterpret_cast<const float4*>(&b1[k4]);
      float4 u;
#define ONE(fld)                                                               \
      {                                                                        \
        float h1a = fmaxf(c0 * ga.fld + c1 * gb.fld + c2 * gc.fld + bb.fld, 0.f); \
        float h1b = fmaxf(d1 * gb.fld + d2 * gc.fld + bb.fld, 0.f);            \
        u.fld = al * h1a + be * h1b;                                           \
      }
      ONE(x) ONE(y) ONE(z) ONE(w)
#undef ONE
      *reinterpret_cast<float4*>(&U[oc]) = u;
    }
  }

  gridbar(cnt, gen);

  // ====== Phase 3: Tp[z] = U @ W2 K-slice partials (KS=4) ======
  // Tile 64x64, BK=32, 4 tiles/block. Grid decode: (4 col, 16 row, 4 K).
  {
    float (*As)[64] = (float (*)[64])smem;
    float (*Bs)[64] = (float (*)[64])(smem + 2048);
    const int tx = tid & 15, ty = tid >> 4;
    const int col0 = (blk & 3) * 64;
    const int row0 = ((blk >> 2) & 15) * 64;
    const int k0 = (blk >> 6) * 128;
    float4 pa[2], pb[2];
    float acc[4][4] = {};

#define LOADG(kb)                                                              \
  {                                                                            \
    _Pragma("unroll") for (int q = 0; q < 2; ++q) {                            \
      int f = tid + q * 256;                                                   \
      int ar = f >> 3, ac = f & 7;                                             \
      pa[q] = *reinterpret_cast<const float4*>(                                \
          &U[(size_t)(row0 + ar) * HH + (kb) + ac * 4]);                       \
    }                                                                          \
    _Pragma("unroll") for (int q = 0; q < 2; ++q) {                            \
      int f = tid + q * 256;                                                   \
      int br = f >> 4, bc = f & 15;                                            \
      pb[q] = *reinterpret_cast<const float4*>(                                \
          &W2[(size_t)((kb) + br) * OO + col0 + bc * 4]);                      \
    }                                                                          \
  }
#define STOLDS()                                                               \
  {                                                                            \
    _Pragma("unroll") for (int q = 0; q < 2; ++q) {                            \
      int f = tid + q * 256;                                                   \
      int ar = f >> 3, ac = f & 7;                                             \
      As[ac * 4 + 0][ar] = pa[q].x;                                            \
      As[ac * 4 + 1][ar] = pa[q].y;                                            \
      As[ac * 4 + 2][ar] = pa[q].z;                                            \
      As[ac * 4 + 3][ar] = pa[q].w;                                            \
    }                                                                          \
    _Pragma("unroll") for (int q = 0; q < 2; ++q) {                            \
      int f = tid + q * 256;                                                   \
      int br = f >> 4, bc = f & 15;                                            \
      *reinterpret_cast<float4*>(&Bs[br][bc * 4]) = pb[q];                     \
    }                                                                          \
  }
#define COMPUTE()                                                              \
  {                                                                            \
    _Pragma("unroll") for (int kk = 0; kk < 32; ++kk) {                        \
      float a[4], b[4];                                                        \
      _Pragma("unroll") for (int i = 0; i < 4; ++i) a[i] = As[kk][ty * 4 + i]; \
      _Pragma("unroll") for (int j = 0; j < 4; ++j) b[j] = Bs[kk][tx * 4 + j]; \
      _Pragma("unroll") for (int i = 0; i < 4; ++i)                            \
          _Pragma("unroll") for (int j = 0; j < 4; ++j)                        \
              acc[i][j] = fmaf(a[i], b[j], acc[i][j]);                         \
    }                                                                          \
  }

    LOADG(k0);
    STOLDS();
    __syncthreads();
    for (int kb = k0 + 32; kb < k0 + 128; kb += 32) {
      LOADG(kb);
      COMPUTE();
      __syncthreads();
      STOLDS();
      __syncthreads();
    }
    COMPUTE();
#undef LOADG
#undef STOLDS
#undef COMPUTE

    float* Pz = Tp + (size_t)(blk >> 6) * ROWS * OO;
#pragma unroll
    for (int i = 0; i < 4; ++i) {
      int r = row0 + ty * 4 + i;
#pragma unroll
      for (int j = 0; j < 4; ++j)
        Pz[(size_t)r * OO + col0 + tx * 4 + j] = acc[i][j];
    }
  }

  gridbar(cnt, gen);

  // ====== Phase 4: out = relu(reduce Tp + b2) @ Wl + bl, 4 rows/block ======
  {
    float* sW = smem;                                  // [256*18]
    float (*sT)[260] = (float (*)[260])(smem + 4608);  // [4][260]
    constexpr size_t TSZ = (size_t)ROWS * OO;
    const int r0 = blk * 4;
    for (int i = tid; i < OO * AA; i += NTHR) sW[i] = Wl[i];
    for (int i = tid; i < 4 * OO; i += NTHR) {
      const int m = i >> 8, k = i & 255;
      const size_t g = (size_t)(r0 + m) * OO + k;
      float s = b2[k];
#pragma unroll
      for (int z = 0; z < 4; ++z) s += Tp[z * TSZ + g];
      sT[m][k] = fmaxf(s, 0.f);
    }
    __syncthreads();
    if (tid < 4 * AA) {
      const int m = tid / AA, o = tid - m * AA;
      float s = bl[o];
#pragma unroll 8
      for (int k = 0; k < OO; ++k) s = fmaf(sT[m][k], sW[k * AA + o], s);
      out[(size_t)(r0 + m) * AA + o] = s;
    }
  }
}

extern "C" void kernel_launch(void* const* d_in, const int* in_sizes, int n_in,
                              void* d_out, int out_size, void* d_ws, size_t ws_size,
                              hipStream_t stream) {
  const float* obs = (const float*)d_in[0];   // [1024, 512]
  const float* W1 = (const float*)d_in[4];    // [512, 512]
  const float* b1 = (const float*)d_in[5];    // [512]
  const float* W2 = (const float*)d_in[6];    // [512, 256]
  const float* b2 = (const float*)d_in[7];    // [256]
  const float* Wl = (const float*)d_in[8];    // [256, 18]
  const float* bl = (const float*)d_in[9];    // [18]
  float* out = (float*)d_out;                 // [1024, 18]

  float* Gp = (float*)d_ws;                         // 2 x 2 MiB
  float* U  = Gp + 2 * (size_t)ROWS * HH;           // 2 MiB
  float* Tp = U + (size_t)ROWS * HH;                // 4 x 1 MiB
  unsigned* bar = (unsigned*)((char*)d_ws + 12u * 1024 * 1024);

  hipMemsetAsync(bar, 0, 2 * sizeof(unsigned), stream);
  fused<<<NBLK, NTHR, 0, stream>>>(obs, W1, b1, W2, b2, Wl, bl, out,
                                   Gp, U, Tp, bar, bar + 1);
}

// Round 8
// 29.099 us; speedup vs baseline: 8.0997x; 8.0997x over previous
//
#include <hip/hip_runtime.h>

// Problem constants: B=16, T=64, N=128, D=512, H=512, O=256, A=18
#define DD 512
#define HH 512
#define OO 256
#define AA 18
#define ROWS 1024

typedef __attribute__((ext_vector_type(8))) short bf16x8;
typedef __attribute__((ext_vector_type(4))) float f32x4;

// f32 -> bf16 round-to-nearest-even (bit trick; inputs are finite).
__device__ __forceinline__ unsigned short f2bf(float x) {
  unsigned u = __builtin_bit_cast(unsigned, x);
  u += 0x7FFFu + ((u >> 16) & 1u);
  return (unsigned short)(u >> 16);
}

// ---------------------------------------------------------------------------
// k1: U(bf16) = pathGCN1(obs @ W1).  Tile 64x32 (64 rows == one batch, so
// t == local row).  512 threads = 2 K-groups x 4 waves; each group does an
// independent K=256 pipeline (8 tiles of BK=32), partials merged in LDS.
// MFMA 16x16x32_bf16; A row-major LDS [64][40], B transposed LDS [32][40]
// (pad 40 shorts = 80 B breaks power-of-2 bank stride).
// Grid: 16 col-tiles x 16 row-tiles = 256 blocks.
// ---------------------------------------------------------------------------
__global__ __launch_bounds__(512) void k1_mfma_combine(
    const float* __restrict__ obs, const float* __restrict__ W1,
    const float* __restrict__ b1, unsigned short* __restrict__ U) {
  __shared__ unsigned short As[2][64][40];
  __shared__ unsigned short Bt[2][32][40];
  __shared__ float Gs[64][36];

  const int tid = threadIdx.x;
  const int g = tid >> 8;              // K-group
  const int gt = tid & 255;
  const int lane = tid & 63;
  const int wid = (tid >> 6) & 3;      // wave within group
  const int col0 = (blockIdx.x & 15) * 32;
  const int row0 = (blockIdx.x >> 4) * 64;
  const int k0 = g * 256;

  const int sar = gt >> 2, sak = (gt & 3) * 8;    // A staging: row, k-ofs
  const int sbc = gt & 31, sbk = (gt >> 5) * 4;   // B staging: col, k-ofs
  const int lr = lane & 15, lk = (lane >> 4) * 8; // fragment indices

  for (int i = tid; i < 64 * 36; i += 512) ((float*)Gs)[i] = 0.f;

  float4 pa0, pa1;
  float pb0, pb1, pb2, pb3;
  f32x4 acc0 = {0.f, 0.f, 0.f, 0.f}, acc1 = {0.f, 0.f, 0.f, 0.f};

#define LOADG(kb)                                                              \
  {                                                                            \
    const float* Ap = &obs[(size_t)(row0 + sar) * DD + (kb) + sak];            \
    pa0 = *reinterpret_cast<const float4*>(Ap);                                \
    pa1 = *reinterpret_cast<const float4*>(Ap + 4);                            \
    const float* Bp = &W1[(size_t)((kb) + sbk) * HH + col0 + sbc];             \
    pb0 = Bp[0]; pb1 = Bp[HH]; pb2 = Bp[2 * HH]; pb3 = Bp[3 * HH];             \
  }
#define STOLDS()                                                               \
  {                                                                            \
    bf16x8 v;                                                                  \
    v[0] = (short)f2bf(pa0.x); v[1] = (short)f2bf(pa0.y);                      \
    v[2] = (short)f2bf(pa0.z); v[3] = (short)f2bf(pa0.w);                      \
    v[4] = (short)f2bf(pa1.x); v[5] = (short)f2bf(pa1.y);                      \
    v[6] = (short)f2bf(pa1.z); v[7] = (short)f2bf(pa1.w);                      \
    *reinterpret_cast<bf16x8*>(&As[g][sar][sak]) = v;                          \
    ushort4 w;                                                                 \
    w.x = f2bf(pb0); w.y = f2bf(pb1); w.z = f2bf(pb2); w.w = f2bf(pb3);        \
    *reinterpret_cast<ushort4*>(&Bt[g][sbc][sbk]) = w;                         \
  }
#define COMPUTE()                                                              \
  {                                                                            \
    const bf16x8 af = *reinterpret_cast<const bf16x8*>(&As[g][wid * 16 + lr][lk]); \
    const bf16x8 bf0 = *reinterpret_cast<const bf16x8*>(&Bt[g][lr][lk]);       \
    const bf16x8 bf1 = *reinterpret_cast<const bf16x8*>(&Bt[g][16 + lr][lk]);  \
    acc0 = __builtin_amdgcn_mfma_f32_16x16x32_bf16(af, bf0, acc0, 0, 0, 0);    \
    acc1 = __builtin_amdgcn_mfma_f32_16x16x32_bf16(af, bf1, acc1, 0, 0, 0);    \
  }

  LOADG(k0);
  STOLDS();
  __syncthreads();
  for (int tt = 1; tt < 8; ++tt) {
    LOADG(k0 + tt * 32);
    COMPUTE();
    __syncthreads();
    STOLDS();
    __syncthreads();
  }
  COMPUTE();
  __syncthreads();
#undef LOADG
#undef STOLDS
#undef COMPUTE

  // Merge both K-groups' accumulators into Gs (f32).
  // C/D layout: col = lane&15, row = (lane>>4)*4 + reg.
  {
    const int crow = wid * 16 + (lane >> 4) * 4;
#pragma unroll
    for (int i = 0; i < 4; ++i) atomicAdd(&Gs[crow + i][lr], acc0[i]);
#pragma unroll
    for (int i = 0; i < 4; ++i) atomicAdd(&Gs[crow + i][16 + lr], acc1[i]);
  }
  __syncthreads();

  // Path-GCN layer-1 combine; t == local row. 512 thr x 4 cols.
  {
    const int rr = tid >> 3;
    const int c4 = (tid & 7) * 4;
    const int t = rr;
    const float is6 = 0.4082482904638630f;  // 1/sqrt(6)
    float c0, c1, c2, d1, d2, al, be;
    if (t <= 1) {
      c0 = 0.f; c1 = 0.f; c2 = 1.f; d1 = 0.f; d2 = 0.f; al = 1.f; be = 0.f;
    } else if (t == 2) {
      c0 = 0.f; c1 = 0.5f; c2 = 0.5f; d1 = 0.5f; d2 = 0.5f; al = 0.5f; be = 0.5f;
    } else {
      c0 = (t == 3) ? is6 : (1.f / 3.f);
      c1 = 1.f / 3.f; c2 = is6;
      d1 = is6; d2 = 0.5f;
      al = is6; be = 0.5f;
    }
    const int rm1 = (t >= 1) ? rr - 1 : rr;
    const int rm2 = (t >= 2) ? rr - 2 : rr;
    ushort4 uo;
    unsigned short* up = (unsigned short*)&uo;
#pragma unroll
    for (int j = 0; j < 4; ++j) {
      const int c = c4 + j;
      const float gc = Gs[rr][c], gb = Gs[rm1][c], ga = Gs[rm2][c];
      const float bb = b1[col0 + c];
      const float h1a = fmaxf(c0 * ga + c1 * gb + c2 * gc + bb, 0.f);
      const float h1b = fmaxf(d1 * gb + d2 * gc + bb, 0.f);
      up[j] = f2bf(al * h1a + be * h1b);
    }
    *reinterpret_cast<ushort4*>(&U[(size_t)(row0 + rr) * HH + col0 + c4]) = uo;
  }
}

// ---------------------------------------------------------------------------
// k2: Tp[z] = U(bf16) @ W2 K-slice partials (KS=4).  Tile 64x32, BK=32,
// 256 threads = 4 waves, MFMA. Grid: (8, 16, 4) = 512 blocks.
// ---------------------------------------------------------------------------
__global__ __launch_bounds__(256) void k2_mfma_sk(
    const unsigned short* __restrict__ U, const float* __restrict__ W2,
    float* __restrict__ Tp) {
  __shared__ unsigned short As[64][40];
  __shared__ unsigned short Bt[32][40];

  const int tid = threadIdx.x;
  const int lane = tid & 63;
  const int wid = tid >> 6;
  const int col0 = blockIdx.x * 32;
  const int row0 = blockIdx.y * 64;
  const int k0 = blockIdx.z * 128;     // Kc = 128, 4 tiles

  const int sar = tid >> 2, sak = (tid & 3) * 8;
  const int sbc = tid & 31, sbk = (tid >> 5) * 4;
  const int lr = lane & 15, lk = (lane >> 4) * 8;

  bf16x8 pa;
  float pb0, pb1, pb2, pb3;
  f32x4 acc0 = {0.f, 0.f, 0.f, 0.f}, acc1 = {0.f, 0.f, 0.f, 0.f};

#define LOADG(kb)                                                              \
  {                                                                            \
    pa = *reinterpret_cast<const bf16x8*>(                                     \
        &U[(size_t)(row0 + sar) * HH + (kb) + sak]);                           \
    const float* Bp = &W2[(size_t)((kb) + sbk) * OO + col0 + sbc];             \
    pb0 = Bp[0]; pb1 = Bp[OO]; pb2 = Bp[2 * OO]; pb3 = Bp[3 * OO];             \
  }
#define STOLDS()                                                               \
  {                                                                            \
    *reinterpret_cast<bf16x8*>(&As[sar][sak]) = pa;                            \
    ushort4 w;                                                                 \
    w.x = f2bf(pb0); w.y = f2bf(pb1); w.z = f2bf(pb2); w.w = f2bf(pb3);        \
    *reinterpret_cast<ushort4*>(&Bt[sbc][sbk]) = w;                            \
  }
#define COMPUTE()                                                              \
  {                                                                            \
    const bf16x8 af = *reinterpret_cast<const bf16x8*>(&As[wid * 16 + lr][lk]);\
    const bf16x8 bf0 = *reinterpret_cast<const bf16x8*>(&Bt[lr][lk]);          \
    const bf16x8 bf1 = *reinterpret_cast<const bf16x8*>(&Bt[16 + lr][lk]);     \
    acc0 = __builtin_amdgcn_mfma_f32_16x16x32_bf16(af, bf0, acc0, 0, 0, 0);    \
    acc1 = __builtin_amdgcn_mfma_f32_16x16x32_bf16(af, bf1, acc1, 0, 0, 0);    \
  }

  LOADG(k0);
  STOLDS();
  __syncthreads();
  for (int tt = 1; tt < 4; ++tt) {
    LOADG(k0 + tt * 32);
    COMPUTE();
    __syncthreads();
    STOLDS();
    __syncthreads();
  }
  COMPUTE();
#undef LOADG
#undef STOLDS
#undef COMPUTE

  float* Pz = Tp + (size_t)blockIdx.z * ROWS * OO;
  const int crow = row0 + wid * 16 + (lane >> 4) * 4;
#pragma unroll
  for (int i = 0; i < 4; ++i) {
    Pz[(size_t)(crow + i) * OO + col0 + lr] = acc0[i];
    Pz[(size_t)(crow + i) * OO + col0 + 16 + lr] = acc1[i];
  }
}

// ---------------------------------------------------------------------------
// k3: reduce 4 partials + b2 + relu -> tgt; out = tgt @ Wl + bl.
// 8 rows/block, 128 blocks (r6-proven shape).
// ---------------------------------------------------------------------------
__global__ __launch_bounds__(256) void k3_head(
    const float* __restrict__ Tp, const float* __restrict__ b2,
    const float* __restrict__ Wl, const float* __restrict__ bl,
    float* __restrict__ out) {
  __shared__ float sW[OO * AA];
  __shared__ float sT[8][OO + 8];

  constexpr size_t TSZ = (size_t)ROWS * OO;
  const int tid = threadIdx.x;
  for (int i = tid; i < OO * AA; i += 256) sW[i] = Wl[i];
  const int r0 = blockIdx.x * 8;
  for (int i = tid; i < 8 * OO; i += 256) {
    const int m = i >> 8, k = i & 255;
    const size_t gp = (size_t)(r0 + m) * OO + k;
    float s = b2[k];
#pragma unroll
    for (int z = 0; z < 4; ++z) s += Tp[z * TSZ + gp];
    sT[m][k] = fmaxf(s, 0.f);
  }
  __syncthreads();

  if (tid < 8 * AA) {
    const int m = tid / AA;
    const int o = tid - m * AA;
    float s = bl[o];
#pragma unroll 8
    for (int k = 0; k < OO; ++k) s = fmaf(sT[m][k], sW[k * AA + o], s);
    out[(size_t)(r0 + m) * AA + o] = s;
  }
}

extern "C" void kernel_launch(void* const* d_in, const int* in_sizes, int n_in,
                              void* d_out, int out_size, void* d_ws, size_t ws_size,
                              hipStream_t stream) {
  const float* obs = (const float*)d_in[0];   // [1024, 512]
  const float* W1 = (const float*)d_in[4];    // [512, 512]
  const float* b1 = (const float*)d_in[5];    // [512]
  const float* W2 = (const float*)d_in[6];    // [512, 256]
  const float* b2 = (const float*)d_in[7];    // [256]
  const float* Wl = (const float*)d_in[8];    // [256, 18]
  const float* bl = (const float*)d_in[9];    // [18]
  float* out = (float*)d_out;                 // [1024, 18]

  unsigned short* U = (unsigned short*)d_ws;                 // 1 MiB bf16
  float* Tp = (float*)((char*)d_ws + (size_t)ROWS * HH * 2); // 4 x 1 MiB f32

  // 1) U = pathGCN1(obs @ W1), MFMA. 256 blocks x 512 thr.
  k1_mfma_combine<<<256, 512, 0, stream>>>(obs, W1, b1, U);

  // 2) Tp = U @ W2 partials, split-K x4. 512 blocks x 256 thr.
  k2_mfma_sk<<<dim3(OO / 32, ROWS / 64, 4), 256, 0, stream>>>(U, W2, Tp);

  // 3) head: reduce + b2 + relu + @Wl + bl. 128 blocks.
  k3_head<<<ROWS / 8, 256, 0, stream>>>(Tp, b2, Wl, bl, out);
}